// Round 9
// baseline (399.996 us; speedup 1.0000x reference)
//
#include <hip/hip_runtime.h>
#include <hip/hip_cooperative_groups.h>
#include <math.h>

namespace cg = cooperative_groups;

#define N_NODES 100000
#define N_EDGES 1600000
#define D 64
#define DOUT 40
#define NBUCK ((N_NODES + 255) / 256)   // 391 buckets of 256 dst-nodes
#define NCHUNK ((N_EDGES + 4095) / 4096) // 391 edge chunks (== NBUCK)

typedef __attribute__((ext_vector_type(8))) short bf16x8v;   // 8 bf16 (4 VGPRs)
typedef __attribute__((ext_vector_type(4))) float f32x4v;    // MFMA accumulator

__device__ inline float bf2f(unsigned u) {
  union { unsigned i; float f; } v;
  v.i = u << 16;
  return v.f;
}
__device__ inline unsigned f2bf(float f) {
  union { float f; unsigned i; } v;
  v.f = f;
  unsigned r = v.i + 0x7fffu + ((v.i >> 16) & 1u);   // RNE
  return r >> 16;
}
__device__ inline void addrow(float* acc, uint4 r) {
  acc[0] += bf2f(r.x & 0xffffu); acc[1] += bf2f(r.x >> 16);
  acc[2] += bf2f(r.y & 0xffffu); acc[3] += bf2f(r.y >> 16);
  acc[4] += bf2f(r.z & 0xffffu); acc[5] += bf2f(r.z >> 16);
  acc[6] += bf2f(r.w & 0xffffu); acc[7] += bf2f(r.w >> 16);
}

// ---------------------------------------------------------------------------
// Cooperative build kernel: cvt + wcvt + CSR bucket sort in ONE launch.
// 391 blocks x 256 threads (co-resident: 32KB LDS, ~64 VGPR).
// P0: feature/weight bf16 cvt (grid-strided) + chunk histogram (dst cached
//     in 16 VGPRs, counts kept in LDS for P2).
// P1: block 0 scans bucket counts.
// P2: chunked LDS counting-sort -> binned (contiguous run writes).
// P3: per-bucket fine sort -> row_start + csr.
// ---------------------------------------------------------------------------
struct BuildArgs {
  const float* x;
  unsigned short* xbf;
  const float* W1l; const float* W1r;
  const float* W2l; const float* W2r; const float* b2;
  unsigned short* Wcat1; unsigned short* Wcat2; float* b2p;
  const int* src; const int* dst;
  int* bcnt; int* bstart; int* bcursor;
  unsigned* binned; int* row_start; int* csr;
};

__global__ __launch_bounds__(256) void build_kernel(BuildArgs a) {
  __shared__ int cnt[512], scn[512], pos[512], base[512];
  __shared__ unsigned ent[4096];          // P1: aliased as scan buffer
  __shared__ unsigned short sbk[4096];
  cg::grid_group grid = cg::this_grid();
  int t = threadIdx.x;
  int blk = blockIdx.x;
  int gtid = blk * 256 + t;
  int nth = gridDim.x * 256;

  // ---- P0a: x -> bf16 (8 floats per item) ----
  const int n8 = N_NODES * D / 8;
  for (int i = gtid; i < n8; i += nth) {
    const float4* p = reinterpret_cast<const float4*>(a.x) + (size_t)i * 2;
    float4 va = p[0], vb = p[1];
    uint4 o;
    o.x = f2bf(va.x) | (f2bf(va.y) << 16);
    o.y = f2bf(va.z) | (f2bf(va.w) << 16);
    o.z = f2bf(vb.x) | (f2bf(vb.y) << 16);
    o.w = f2bf(vb.z) | (f2bf(vb.w) << 16);
    reinterpret_cast<uint4*>(a.xbf)[i] = o;
  }
  // ---- P0b: weight prep ----
  const int NW = 64 * 128 + 48 * 128 + 48;
  for (int i = gtid; i < NW; i += nth) {
    if (i < 64 * 128) {
      int o = i >> 7, k = i & 127;
      float v = (k < 64) ? a.W1l[o * 64 + k] : a.W1r[o * 64 + (k - 64)];
      a.Wcat1[i] = (unsigned short)f2bf(v);
    } else if (i < 64 * 128 + 48 * 128) {
      int j = i - 64 * 128;
      int o = j >> 7, k = j & 127;
      float v = (o < DOUT) ? ((k < 64) ? a.W2l[o * 64 + k] : a.W2r[o * 64 + (k - 64)]) : 0.0f;
      a.Wcat2[j] = (unsigned short)f2bf(v);
    } else {
      int j = i - 64 * 128 - 48 * 128;
      a.b2p[j] = (j < DOUT) ? a.b2[j] : 0.0f;
    }
  }
  // ---- P0c: chunk histogram; cache dst in registers ----
  cnt[t] = 0; cnt[t + 256] = 0;
  __syncthreads();
  int cbase = blk * 4096;
  int cc = min(4096, N_EDGES - cbase);
  int my_d[16];
#pragma unroll
  for (int i = 0; i < 16; ++i) {
    int li = t + i * 256;
    my_d[i] = (li < cc) ? a.dst[cbase + li] : -1;
    if (li < cc) atomicAdd(&cnt[my_d[i] >> 8], 1);
  }
  __syncthreads();
  for (int b = t; b < NBUCK; b += 256)
    if (cnt[b]) atomicAdd(&a.bcnt[b], cnt[b]);
  __threadfence();
  grid.sync();

  // ---- P1: block 0 scans bucket counts ----
  if (blk == 0) {
    int* sc = (int*)ent;
    int o0 = (t < NBUCK) ? a.bcnt[t] : 0;
    int o1 = (t + 256 < NBUCK) ? a.bcnt[t + 256] : 0;
    sc[t] = o0; sc[t + 256] = o1;
    __syncthreads();
    for (int off = 1; off < 512; off <<= 1) {
      int v0 = (t >= off) ? sc[t - off] : 0;
      int v1 = sc[t + 256 - off];
      __syncthreads();
      sc[t] += v0; sc[t + 256] += v1;
      __syncthreads();
    }
    if (t < NBUCK) { a.bstart[t] = sc[t] - o0; a.bcursor[t] = sc[t] - o0; }
    if (t + 256 < NBUCK) { a.bstart[t + 256] = sc[t + 256] - o1; a.bcursor[t + 256] = sc[t + 256] - o1; }
    if (t == 0) a.bstart[NBUCK] = N_EDGES;
    __threadfence();
  }
  grid.sync();

  // ---- P2: scatter chunk -> binned (reuses cached my_d + LDS cnt) ----
  scn[t] = cnt[t]; scn[t + 256] = cnt[t + 256];
  __syncthreads();
  for (int off = 1; off < 512; off <<= 1) {
    int v0 = (t >= off) ? scn[t - off] : 0;
    int v1 = scn[t + 256 - off];
    __syncthreads();
    scn[t] += v0; scn[t + 256] += v1;
    __syncthreads();
  }
  pos[t] = scn[t] - cnt[t];
  pos[t + 256] = scn[t + 256] - cnt[t + 256];
  __syncthreads();
#pragma unroll
  for (int i = 0; i < 16; ++i) {
    int li = t + i * 256;
    if (li < cc) {
      int s = a.src[cbase + li];
      int d = my_d[i];
      int b = d >> 8;
      int slot = atomicAdd(&pos[b], 1);
      ent[slot] = ((unsigned)(d & 255) << 24) | (unsigned)s;
      sbk[slot] = (unsigned short)b;
    }
  }
  __syncthreads();
  for (int b = t; b < NBUCK; b += 256)
    if (cnt[b] > 0) base[b] = atomicAdd(&a.bcursor[b], cnt[b]);
  __syncthreads();
  for (int i = t; i < cc; i += 256) {
    int b = sbk[i];
    int excl = scn[b] - cnt[b];
    a.binned[base[b] + (i - excl)] = ent[i];
  }
  __threadfence();
  grid.sync();

  // ---- P3: per-bucket fine sort -> row_start + csr ----
  int s0 = a.bstart[blk], s1 = a.bstart[blk + 1];
  cnt[t] = 0;                 // reuse cnt[0..255] as fine counts
  __syncthreads();
  for (int i = s0 + t; i < s1; i += 256)
    atomicAdd(&cnt[a.binned[i] >> 24], 1);
  __syncthreads();
  scn[t] = cnt[t];
  __syncthreads();
  for (int off = 1; off < 256; off <<= 1) {
    int v = (t >= off) ? scn[t - off] : 0;
    __syncthreads();
    scn[t] += v;
    __syncthreads();
  }
  int excl = scn[t] - cnt[t];
  int node = blk * 256 + t;
  if (node < N_NODES) a.row_start[node] = s0 + excl;
  if (blk == 0 && t == 0) a.row_start[N_NODES] = N_EDGES;
  pos[t] = excl;
  __syncthreads();
  for (int i = s0 + t; i < s1; i += 256) {
    unsigned u = a.binned[i];
    int slot = atomicAdd(&pos[u >> 24], 1);
    a.csr[s0 + slot] = (int)(u & 0xFFFFFFu);
  }
}

// ---------------------------------------------------------------------------
// Aggregation: one wave per node, zero LDS. 8 groups x 8 lanes; butterfly
// fold; lane (g,t) writes feature t*8+g of the bf16 mean row.
// ---------------------------------------------------------------------------
__global__ __launch_bounds__(256) void agg_kernel(
    const unsigned short* __restrict__ feat, const int* __restrict__ row_start,
    const int* __restrict__ csr, unsigned short* __restrict__ msbf, int N) {
  int wid = (blockIdx.x * 256 + threadIdx.x) >> 6;
  if (wid >= N) return;
  int lane = threadIdx.x & 63;
  int g = lane >> 3;
  int t = lane & 7;
  int rs = row_start[wid], re = row_start[wid + 1];
  float acc[8] = {0.f, 0.f, 0.f, 0.f, 0.f, 0.f, 0.f, 0.f};
  int e = rs + g;
  for (; e + 8 < re; e += 16) {
    int s0 = csr[e];
    int s1 = csr[e + 8];
    uint4 r0 = *reinterpret_cast<const uint4*>(feat + (size_t)s0 * D + t * 8);
    uint4 r1 = *reinterpret_cast<const uint4*>(feat + (size_t)s1 * D + t * 8);
    addrow(acc, r0);
    addrow(acc, r1);
  }
  if (e < re) {
    int s0 = csr[e];
    uint4 r0 = *reinterpret_cast<const uint4*>(feat + (size_t)s0 * D + t * 8);
    addrow(acc, r0);
  }
#pragma unroll
  for (int j = 0; j < 8; ++j) {
    acc[j] += __shfl_xor(acc[j], 8, 64);
    acc[j] += __shfl_xor(acc[j], 16, 64);
    acc[j] += __shfl_xor(acc[j], 32, 64);
  }
  float inv = 1.0f / fmaxf((float)(re - rs), 1.0f);
  float mv = acc[0];
#pragma unroll
  for (int j = 1; j < 8; ++j)
    if (g == j) mv = acc[j];      // static-index cndmask chain (no scratch)
  msbf[(size_t)wid * D + t * 8 + g] = (unsigned short)f2bf(mv * inv);
}

// ---------------------------------------------------------------------------
// MFMA linear 1: h = relu([ms|x] @ Wcat1^T + b1), one wave per 16-node tile.
// C/D: col=lane&15, row=(lane>>4)*4+reg  [m89-verified].
// ---------------------------------------------------------------------------
__global__ __launch_bounds__(256) void lin1_kernel(
    const unsigned short* __restrict__ xbf, const unsigned short* __restrict__ msbf,
    const unsigned short* __restrict__ Wcat, const float* __restrict__ b1,
    unsigned short* __restrict__ hbf, int N) {
  int wid = (blockIdx.x * 256 + threadIdx.x) >> 6;   // tile id
  int ntiles = N >> 4;                               // 6250
  if (wid >= ntiles) return;
  int lane = threadIdx.x & 63;
  int col = lane & 15;
  int k0 = (lane >> 4) * 8;
  int base = wid * 16;
  const unsigned short* am = msbf + (size_t)(base + col) * D;
  const unsigned short* ax = xbf + (size_t)(base + col) * D;
  bf16x8v a0 = *(const bf16x8v*)(am + k0);
  bf16x8v a1 = *(const bf16x8v*)(am + 32 + k0);
  bf16x8v a2 = *(const bf16x8v*)(ax + k0);
  bf16x8v a3 = *(const bf16x8v*)(ax + 32 + k0);
  f32x4v acc0 = {0.f, 0.f, 0.f, 0.f}, acc1 = acc0, acc2 = acc0, acc3 = acc0;
#define LIN1_CT(CT, ACC)                                                      \
  {                                                                           \
    const unsigned short* w = Wcat + ((CT)*16 + col) * 128 + k0;              \
    bf16x8v b0 = *(const bf16x8v*)(w);                                        \
    bf16x8v b1v = *(const bf16x8v*)(w + 32);                                  \
    bf16x8v b2v = *(const bf16x8v*)(w + 64);                                  \
    bf16x8v b3v = *(const bf16x8v*)(w + 96);                                  \
    ACC = __builtin_amdgcn_mfma_f32_16x16x32_bf16(a0, b0, ACC, 0, 0, 0);      \
    ACC = __builtin_amdgcn_mfma_f32_16x16x32_bf16(a1, b1v, ACC, 0, 0, 0);     \
    ACC = __builtin_amdgcn_mfma_f32_16x16x32_bf16(a2, b2v, ACC, 0, 0, 0);     \
    ACC = __builtin_amdgcn_mfma_f32_16x16x32_bf16(a3, b3v, ACC, 0, 0, 0);     \
  }
  LIN1_CT(0, acc0) LIN1_CT(1, acc1) LIN1_CT(2, acc2) LIN1_CT(3, acc3)
#undef LIN1_CT
  int rbase = (lane >> 4) * 4;
  float bias0 = b1[col], bias1 = b1[16 + col], bias2 = b1[32 + col], bias3 = b1[48 + col];
#pragma unroll
  for (int r = 0; r < 4; ++r) {
    size_t rowoff = (size_t)(base + rbase + r) * D;
    hbf[rowoff + col]      = (unsigned short)f2bf(fmaxf(acc0[r] + bias0, 0.f));
    hbf[rowoff + 16 + col] = (unsigned short)f2bf(fmaxf(acc1[r] + bias1, 0.f));
    hbf[rowoff + 32 + col] = (unsigned short)f2bf(fmaxf(acc2[r] + bias2, 0.f));
    hbf[rowoff + 48 + col] = (unsigned short)f2bf(fmaxf(acc3[r] + bias3, 0.f));
  }
}

// ---------------------------------------------------------------------------
// MFMA linear 2 + log_softmax (48 cols, 40 valid; 16-lane shfl reduction)
// ---------------------------------------------------------------------------
__global__ __launch_bounds__(256) void lin2_kernel(
    const unsigned short* __restrict__ hbf, const unsigned short* __restrict__ msbf,
    const unsigned short* __restrict__ Wcat, const float* __restrict__ b2p,
    float* __restrict__ out, int N) {
  int wid = (blockIdx.x * 256 + threadIdx.x) >> 6;
  int ntiles = N >> 4;
  if (wid >= ntiles) return;
  int lane = threadIdx.x & 63;
  int col = lane & 15;
  int k0 = (lane >> 4) * 8;
  int base = wid * 16;
  const unsigned short* am = msbf + (size_t)(base + col) * D;
  const unsigned short* ah = hbf + (size_t)(base + col) * D;
  bf16x8v a0 = *(const bf16x8v*)(am + k0);
  bf16x8v a1 = *(const bf16x8v*)(am + 32 + k0);
  bf16x8v a2 = *(const bf16x8v*)(ah + k0);
  bf16x8v a3 = *(const bf16x8v*)(ah + 32 + k0);
  f32x4v acc0 = {0.f, 0.f, 0.f, 0.f}, acc1 = acc0, acc2 = acc0;
#define LIN2_CT(CT, ACC)                                                      \
  {                                                                           \
    const unsigned short* w = Wcat + ((CT)*16 + col) * 128 + k0;              \
    bf16x8v b0 = *(const bf16x8v*)(w);                                        \
    bf16x8v b1v = *(const bf16x8v*)(w + 32);                                  \
    bf16x8v b2v = *(const bf16x8v*)(w + 64);                                  \
    bf16x8v b3v = *(const bf16x8v*)(w + 96);                                  \
    ACC = __builtin_amdgcn_mfma_f32_16x16x32_bf16(a0, b0, ACC, 0, 0, 0);      \
    ACC = __builtin_amdgcn_mfma_f32_16x16x32_bf16(a1, b1v, ACC, 0, 0, 0);     \
    ACC = __builtin_amdgcn_mfma_f32_16x16x32_bf16(a2, b2v, ACC, 0, 0, 0);     \
    ACC = __builtin_amdgcn_mfma_f32_16x16x32_bf16(a3, b3v, ACC, 0, 0, 0);     \
  }
  LIN2_CT(0, acc0) LIN2_CT(1, acc1) LIN2_CT(2, acc2)
#undef LIN2_CT
  int rbase = (lane >> 4) * 4;
  float bias0 = b2p[col], bias1 = b2p[16 + col], bias2 = b2p[32 + col];
  bool v2ok = (col < 8);   // cols 32..39 valid only
#pragma unroll
  for (int r = 0; r < 4; ++r) {
    float v0 = acc0[r] + bias0;
    float v1 = acc1[r] + bias1;
    float v2 = v2ok ? (acc2[r] + bias2) : -INFINITY;
    float mx = fmaxf(fmaxf(v0, v1), v2);
    mx = fmaxf(mx, __shfl_xor(mx, 1, 64));
    mx = fmaxf(mx, __shfl_xor(mx, 2, 64));
    mx = fmaxf(mx, __shfl_xor(mx, 4, 64));
    mx = fmaxf(mx, __shfl_xor(mx, 8, 64));
    float sm = expf(v0 - mx) + expf(v1 - mx) + (v2ok ? expf(v2 - mx) : 0.f);
    sm += __shfl_xor(sm, 1, 64);
    sm += __shfl_xor(sm, 2, 64);
    sm += __shfl_xor(sm, 4, 64);
    sm += __shfl_xor(sm, 8, 64);
    float ls = mx + logf(sm);
    size_t rowoff = (size_t)(base + rbase + r) * DOUT;
    out[rowoff + col] = v0 - ls;
    out[rowoff + 16 + col] = v1 - ls;
    if (v2ok) out[rowoff + 32 + col] = v2 - ls;
  }
}

extern "C" void kernel_launch(void* const* d_in, const int* in_sizes, int n_in,
                              void* d_out, int out_size, void* d_ws, size_t ws_size,
                              hipStream_t stream) {
  const float* x   = (const float*)d_in[0];
  const int*   ei  = (const int*)d_in[1];
  const float* W1l = (const float*)d_in[2];
  const float* b1  = (const float*)d_in[3];
  const float* W1r = (const float*)d_in[4];
  const float* W2l = (const float*)d_in[5];
  const float* b2  = (const float*)d_in[6];
  const float* W2r = (const float*)d_in[7];
  float* out = (float*)d_out;

  const int* src = ei;
  const int* dst = ei + N_EDGES;

  // Workspace (~45.3 MB): xbf | hbf | csr | row_start | bcnt/bstart/bcursor |
  // scratch(12.8M: binned then ms1) | Wcat1 | Wcat2 | b2p.  ms2 aliases xbf.
  char* ws = (char*)d_ws;
  size_t featB = (size_t)N_NODES * D * sizeof(unsigned short);  // 12.8 MB
  unsigned short* xbf = (unsigned short*)ws;
  unsigned short* hbf = (unsigned short*)(ws + featB);
  int* csr       = (int*)(ws + 2 * featB);                      // 6.4 MB
  int* row_start = csr + N_EDGES;                               // (N+1) ints
  int* bcnt      = row_start + N_NODES + 1;
  int* bstart    = bcnt + NBUCK;
  int* bcursor   = bstart + NBUCK + 1;
  char* scratch  = (char*)(bcursor + NBUCK);
  scratch = (char*)(((uintptr_t)scratch + 15) & ~(uintptr_t)15);
  unsigned* binned     = (unsigned*)scratch;                    // 6.4 MB
  unsigned short* ms1  = (unsigned short*)scratch;              // 12.8 MB (after build)
  unsigned short* ms2  = xbf;                                   // after lin1
  unsigned short* Wcat1 = (unsigned short*)(scratch + featB);
  unsigned short* Wcat2 = Wcat1 + 64 * 128;
  float* b2p            = (float*)(Wcat2 + 48 * 128);

  const int AGG_BLOCKS = (N_NODES + 3) / 4;       // one wave per node
  const int LIN_BLOCKS = ((N_NODES / 16) + 3) / 4;

  // ---- fused preprocessing (cvt + wcvt + CSR build), one cooperative launch ----
  hipMemsetAsync(bcnt, 0, NBUCK * sizeof(int), stream);
  BuildArgs ba;
  ba.x = x; ba.xbf = xbf;
  ba.W1l = W1l; ba.W1r = W1r; ba.W2l = W2l; ba.W2r = W2r; ba.b2 = b2;
  ba.Wcat1 = Wcat1; ba.Wcat2 = Wcat2; ba.b2p = b2p;
  ba.src = src; ba.dst = dst;
  ba.bcnt = bcnt; ba.bstart = bstart; ba.bcursor = bcursor;
  ba.binned = binned; ba.row_start = row_start; ba.csr = csr;
  void* kargs[] = {&ba};
  hipLaunchCooperativeKernel((const void*)build_kernel, dim3(NCHUNK), dim3(256),
                             kargs, 0, stream);

  // ---- layer 1 ----
  agg_kernel<<<AGG_BLOCKS, 256, 0, stream>>>(xbf, row_start, csr, ms1, N_NODES);
  lin1_kernel<<<LIN_BLOCKS, 256, 0, stream>>>(xbf, ms1, Wcat1, b1, hbf, N_NODES);

  // ---- layer 2 ----
  agg_kernel<<<AGG_BLOCKS, 256, 0, stream>>>(hbf, row_start, csr, ms2, N_NODES);
  lin2_kernel<<<LIN_BLOCKS, 256, 0, stream>>>(hbf, ms2, Wcat2, b2p, out, N_NODES);
}

// Round 10
// 302.860 us; speedup vs baseline: 1.3207x; 1.3207x over previous
//
#include <hip/hip_runtime.h>
#include <math.h>

#define N_NODES 100000
#define N_EDGES 1600000
#define D 64
#define DOUT 40
#define NBUCK ((N_NODES + 255) / 256)   // 391 buckets of 256 dst-nodes

typedef __attribute__((ext_vector_type(8))) short bf16x8v;   // 8 bf16 (4 VGPRs)
typedef __attribute__((ext_vector_type(4))) float f32x4v;    // MFMA accumulator

#define PLANE ((size_t)N_NODES * 16)    // elements per feature quarter-plane

__device__ inline float bf2f(unsigned u) {
  union { unsigned i; float f; } v;
  v.i = u << 16;
  return v.f;
}
__device__ inline unsigned f2bf(float f) {
  union { float f; unsigned i; } v;
  v.f = f;
  unsigned r = v.i + 0x7fffu + ((v.i >> 16) & 1u);   // RNE
  return r >> 16;
}

// ---------------------------------------------------------------------------
// f32 -> bf16 convert into quarter-plane layout [4][N][16].
// Thread i handles node n=i/8, k0=(i%8)*8 -> plane k0>>4, in-plane off k0&15.
// ---------------------------------------------------------------------------
__global__ __launch_bounds__(256) void cvt_kernel(const float* __restrict__ in,
                                                  unsigned short* __restrict__ ob,
                                                  int n8) {
  int i = blockIdx.x * 256 + threadIdx.x;
  if (i >= n8) return;
  const float4* p = reinterpret_cast<const float4*>(in) + (size_t)i * 2;
  float4 a = p[0], b = p[1];
  uint4 o;
  o.x = f2bf(a.x) | (f2bf(a.y) << 16);
  o.y = f2bf(a.z) | (f2bf(a.w) << 16);
  o.z = f2bf(b.x) | (f2bf(b.y) << 16);
  o.w = f2bf(b.z) | (f2bf(b.w) << 16);
  int n = i >> 3;
  int k0 = (i & 7) * 8;
  size_t idx = (size_t)(k0 >> 4) * PLANE + (size_t)n * 16 + (k0 & 15);
  *reinterpret_cast<uint4*>(ob + idx) = o;
}

// ---------------------------------------------------------------------------
// Weight prep: Wcat1[64][128] = [W1l | W1r] bf16; Wcat2[48][128] = [W2l | W2r]
// (rows 40..47 zero); b2p[48] padded bias.
// ---------------------------------------------------------------------------
__global__ __launch_bounds__(256) void wcvt_kernel(
    const float* __restrict__ W1l, const float* __restrict__ W1r,
    const float* __restrict__ W2l, const float* __restrict__ W2r,
    const float* __restrict__ b2, unsigned short* __restrict__ Wcat1,
    unsigned short* __restrict__ Wcat2, float* __restrict__ b2p) {
  int i = blockIdx.x * 256 + threadIdx.x;
  if (i < 64 * 128) {
    int o = i >> 7, k = i & 127;
    float v = (k < 64) ? W1l[o * 64 + k] : W1r[o * 64 + (k - 64)];
    Wcat1[i] = (unsigned short)f2bf(v);
  } else if (i < 64 * 128 + 48 * 128) {
    int j = i - 64 * 128;
    int o = j >> 7, k = j & 127;
    float v = (o < DOUT) ? ((k < 64) ? W2l[o * 64 + k] : W2r[o * 64 + (k - 64)]) : 0.0f;
    Wcat2[j] = (unsigned short)f2bf(v);
  } else if (i < 64 * 128 + 48 * 128 + 48) {
    int j = i - 64 * 128 - 48 * 128;
    b2p[j] = (j < DOUT) ? b2[j] : 0.0f;
  }
}

// ---------------------------------------------------------------------------
// CSR build: two-level bucket sort (write-locality-aware) — R8-proven
// ---------------------------------------------------------------------------
__global__ __launch_bounds__(256) void bhist_kernel(const int* __restrict__ dst,
                                                    int* __restrict__ bcnt, int E) {
  __shared__ int c[512];
  int t = threadIdx.x;
  c[t] = 0; c[t + 256] = 0;
  __syncthreads();
  int cbase = blockIdx.x * 4096;
  int cc = min(4096, E - cbase);
  for (int i = t; i < cc; i += 256) atomicAdd(&c[dst[cbase + i] >> 8], 1);
  __syncthreads();
  for (int b = t; b < NBUCK; b += 256)
    if (c[b]) atomicAdd(&bcnt[b], c[b]);
}

__global__ __launch_bounds__(256) void bscan_kernel(const int* __restrict__ bcnt,
                                                    int* __restrict__ bstart,
                                                    int* __restrict__ bcursor, int E) {
  __shared__ int s[512];
  int t = threadIdx.x;
  int o0 = (t < NBUCK) ? bcnt[t] : 0;
  int o1 = (t + 256 < NBUCK) ? bcnt[t + 256] : 0;
  s[t] = o0; s[t + 256] = o1;
  __syncthreads();
  for (int off = 1; off < 512; off <<= 1) {
    int v0 = (t >= off) ? s[t - off] : 0;
    int v1 = s[t + 256 - off];
    __syncthreads();
    s[t] += v0; s[t + 256] += v1;
    __syncthreads();
  }
  if (t < NBUCK) { bstart[t] = s[t] - o0; bcursor[t] = s[t] - o0; }
  if (t + 256 < NBUCK) { bstart[t + 256] = s[t + 256] - o1; bcursor[t + 256] = s[t + 256] - o1; }
  if (t == 0) bstart[NBUCK] = E;
}

__global__ __launch_bounds__(256) void bscatter_kernel(const int* __restrict__ src,
                                                       const int* __restrict__ dst,
                                                       int* __restrict__ bcursor,
                                                       unsigned* __restrict__ binned,
                                                       int E) {
  __shared__ unsigned ent[4096];
  __shared__ unsigned short sbk[4096];
  __shared__ int cnt[512], scn[512], pos[512], base[512];
  int t = threadIdx.x;
  int cbase = blockIdx.x * 4096;
  int cc = min(4096, E - cbase);
  cnt[t] = 0; cnt[t + 256] = 0;
  __syncthreads();
  unsigned my_e[16];
  int my_b[16];
  int nmine = 0;
#pragma unroll
  for (int i = 0; i < 16; ++i) {
    int li = t + i * 256;
    if (li < cc) {
      int s = src[cbase + li];
      int d = dst[cbase + li];
      int b = d >> 8;
      my_e[nmine] = ((unsigned)(d & 255) << 24) | (unsigned)s;
      my_b[nmine] = b;
      nmine++;
      atomicAdd(&cnt[b], 1);
    }
  }
  __syncthreads();
  scn[t] = cnt[t]; scn[t + 256] = cnt[t + 256];
  __syncthreads();
  for (int off = 1; off < 512; off <<= 1) {
    int v0 = (t >= off) ? scn[t - off] : 0;
    int v1 = scn[t + 256 - off];
    __syncthreads();
    scn[t] += v0; scn[t + 256] += v1;
    __syncthreads();
  }
  pos[t] = scn[t] - cnt[t];
  pos[t + 256] = scn[t + 256] - cnt[t + 256];
  __syncthreads();
  for (int i = 0; i < nmine; ++i) {
    int slot = atomicAdd(&pos[my_b[i]], 1);
    ent[slot] = my_e[i];
    sbk[slot] = (unsigned short)my_b[i];
  }
  __syncthreads();
  for (int b = t; b < NBUCK; b += 256)
    if (cnt[b] > 0) base[b] = atomicAdd(&bcursor[b], cnt[b]);
  __syncthreads();
  for (int i = t; i < cc; i += 256) {
    int b = sbk[i];
    int excl = scn[b] - cnt[b];
    binned[base[b] + (i - excl)] = ent[i];
  }
}

__global__ __launch_bounds__(256) void bfine_kernel(const unsigned* __restrict__ binned,
                                                    const int* __restrict__ bstart,
                                                    int* __restrict__ row_start,
                                                    int* __restrict__ csr, int N, int E) {
  __shared__ int c[256], p[256], pos[256];
  int b = blockIdx.x;
  int t = threadIdx.x;
  int s0 = bstart[b], s1 = bstart[b + 1];
  c[t] = 0;
  __syncthreads();
  for (int i = s0 + t; i < s1; i += 256)
    atomicAdd(&c[binned[i] >> 24], 1);
  __syncthreads();
  p[t] = c[t];
  __syncthreads();
  for (int off = 1; off < 256; off <<= 1) {
    int v = (t >= off) ? p[t - off] : 0;
    __syncthreads();
    p[t] += v;
    __syncthreads();
  }
  int excl = p[t] - c[t];
  int node = b * 256 + t;
  if (node < N) row_start[node] = s0 + excl;
  if (b == 0 && t == 0) row_start[N] = E;
  pos[t] = excl;
  __syncthreads();
  for (int i = s0 + t; i < s1; i += 256) {
    unsigned u = binned[i];
    int slot = atomicAdd(&pos[u >> 24], 1);
    csr[s0 + slot] = (int)(u & 0xFFFFFFu);
  }
}

// ---------------------------------------------------------------------------
// Quartered aggregation: wave = (node, quarter). Quarter = (bid%8)>>1 so each
// XCD pair's L2 serves one 3.2MB plane (< 4MiB L2). 16 edge-groups x 4 lanes,
// 8B loads; fold via shfl_xor(4,8,16,32); g==0 lanes write 8B each (32B/node).
// ---------------------------------------------------------------------------
__global__ __launch_bounds__(256) void agg_kernel(
    const unsigned short* __restrict__ featq, const int* __restrict__ row_start,
    const int* __restrict__ csr, unsigned short* __restrict__ msq, int N) {
  int bid = blockIdx.x;
  int q = (bid & 7) >> 1;                        // XCD-pair quarter
  int j = ((bid >> 3) << 1) | (bid & 1);         // [0, N/4) per quarter
  int wave = threadIdx.x >> 6;
  int node = j * 4 + wave;
  if (node >= N) return;
  int lane = threadIdx.x & 63;
  int g = lane >> 2;                             // edge group 0..15
  int t = lane & 3;                              // 4-feature chunk (8B)
  const unsigned short* plane = featq + (size_t)q * PLANE;
  int rs = row_start[node], re = row_start[node + 1];
  float a0 = 0.f, a1 = 0.f, a2 = 0.f, a3 = 0.f;
  int e = rs + g;
  for (; e + 16 < re; e += 32) {
    int s0 = csr[e];
    int s1 = csr[e + 16];
    uint2 r0 = *reinterpret_cast<const uint2*>(plane + (size_t)s0 * 16 + t * 4);
    uint2 r1 = *reinterpret_cast<const uint2*>(plane + (size_t)s1 * 16 + t * 4);
    a0 += bf2f(r0.x & 0xffffu) + bf2f(r1.x & 0xffffu);
    a1 += bf2f(r0.x >> 16) + bf2f(r1.x >> 16);
    a2 += bf2f(r0.y & 0xffffu) + bf2f(r1.y & 0xffffu);
    a3 += bf2f(r0.y >> 16) + bf2f(r1.y >> 16);
  }
  if (e < re) {
    int s0 = csr[e];
    uint2 r0 = *reinterpret_cast<const uint2*>(plane + (size_t)s0 * 16 + t * 4);
    a0 += bf2f(r0.x & 0xffffu);
    a1 += bf2f(r0.x >> 16);
    a2 += bf2f(r0.y & 0xffffu);
    a3 += bf2f(r0.y >> 16);
  }
#pragma unroll
  for (int off = 4; off <= 32; off <<= 1) {
    a0 += __shfl_xor(a0, off, 64);
    a1 += __shfl_xor(a1, off, 64);
    a2 += __shfl_xor(a2, off, 64);
    a3 += __shfl_xor(a3, off, 64);
  }
  if (g == 0) {
    float inv = 1.0f / fmaxf((float)(re - rs), 1.0f);
    uint2 o;
    o.x = f2bf(a0 * inv) | (f2bf(a1 * inv) << 16);
    o.y = f2bf(a2 * inv) | (f2bf(a3 * inv) << 16);
    *reinterpret_cast<uint2*>(msq + (size_t)q * PLANE + (size_t)node * 16 + t * 4) = o;
  }
}

// ---------------------------------------------------------------------------
// MFMA linear 1 (plane-layout inputs/outputs):
// A k-chunks: k0=(lane>>4)*8; ms feats k0 -> plane k0>>4; feats 32+k0 -> +2.
// C/D: col=lane&15, row=(lane>>4)*4+reg [m89]. acc_j -> output plane j.
// ---------------------------------------------------------------------------
__global__ __launch_bounds__(256) void lin1_kernel(
    const unsigned short* __restrict__ xq, const unsigned short* __restrict__ msq,
    const unsigned short* __restrict__ Wcat, const float* __restrict__ b1,
    unsigned short* __restrict__ hq, int N) {
  int wid = (blockIdx.x * 256 + threadIdx.x) >> 6;   // tile id
  int ntiles = N >> 4;                               // 6250
  if (wid >= ntiles) return;
  int lane = threadIdx.x & 63;
  int col = lane & 15;
  int k0 = (lane >> 4) * 8;
  int p = k0 >> 4;                                   // 0,0,1,1
  int o16 = k0 & 15;                                 // 0,8
  int base = wid * 16;
  size_t rowo = (size_t)(base + col) * 16 + o16;
  bf16x8v a0 = *(const bf16x8v*)(msq + (size_t)p * PLANE + rowo);
  bf16x8v a1 = *(const bf16x8v*)(msq + (size_t)(p + 2) * PLANE + rowo);
  bf16x8v a2 = *(const bf16x8v*)(xq + (size_t)p * PLANE + rowo);
  bf16x8v a3 = *(const bf16x8v*)(xq + (size_t)(p + 2) * PLANE + rowo);
  f32x4v acc0 = {0.f, 0.f, 0.f, 0.f}, acc1 = acc0, acc2 = acc0, acc3 = acc0;
#define LIN1_CT(CT, ACC)                                                      \
  {                                                                           \
    const unsigned short* w = Wcat + ((CT)*16 + col) * 128 + k0;              \
    bf16x8v b0 = *(const bf16x8v*)(w);                                        \
    bf16x8v b1v = *(const bf16x8v*)(w + 32);                                  \
    bf16x8v b2v = *(const bf16x8v*)(w + 64);                                  \
    bf16x8v b3v = *(const bf16x8v*)(w + 96);                                  \
    ACC = __builtin_amdgcn_mfma_f32_16x16x32_bf16(a0, b0, ACC, 0, 0, 0);      \
    ACC = __builtin_amdgcn_mfma_f32_16x16x32_bf16(a1, b1v, ACC, 0, 0, 0);     \
    ACC = __builtin_amdgcn_mfma_f32_16x16x32_bf16(a2, b2v, ACC, 0, 0, 0);     \
    ACC = __builtin_amdgcn_mfma_f32_16x16x32_bf16(a3, b3v, ACC, 0, 0, 0);     \
  }
  LIN1_CT(0, acc0) LIN1_CT(1, acc1) LIN1_CT(2, acc2) LIN1_CT(3, acc3)
#undef LIN1_CT
  int rbase = (lane >> 4) * 4;
  float bias0 = b1[col], bias1 = b1[16 + col], bias2 = b1[32 + col], bias3 = b1[48 + col];
#pragma unroll
  for (int r = 0; r < 4; ++r) {
    size_t ro = (size_t)(base + rbase + r) * 16 + col;
    hq[ro]              = (unsigned short)f2bf(fmaxf(acc0[r] + bias0, 0.f));
    hq[PLANE + ro]      = (unsigned short)f2bf(fmaxf(acc1[r] + bias1, 0.f));
    hq[2 * PLANE + ro]  = (unsigned short)f2bf(fmaxf(acc2[r] + bias2, 0.f));
    hq[3 * PLANE + ro]  = (unsigned short)f2bf(fmaxf(acc3[r] + bias3, 0.f));
  }
}

// ---------------------------------------------------------------------------
// MFMA linear 2 + log_softmax (plane-layout inputs; f32 row-major out)
// ---------------------------------------------------------------------------
__global__ __launch_bounds__(256) void lin2_kernel(
    const unsigned short* __restrict__ hq, const unsigned short* __restrict__ msq,
    const unsigned short* __restrict__ Wcat, const float* __restrict__ b2p,
    float* __restrict__ out, int N) {
  int wid = (blockIdx.x * 256 + threadIdx.x) >> 6;
  int ntiles = N >> 4;
  if (wid >= ntiles) return;
  int lane = threadIdx.x & 63;
  int col = lane & 15;
  int k0 = (lane >> 4) * 8;
  int p = k0 >> 4;
  int o16 = k0 & 15;
  int base = wid * 16;
  size_t rowo = (size_t)(base + col) * 16 + o16;
  bf16x8v a0 = *(const bf16x8v*)(msq + (size_t)p * PLANE + rowo);
  bf16x8v a1 = *(const bf16x8v*)(msq + (size_t)(p + 2) * PLANE + rowo);
  bf16x8v a2 = *(const bf16x8v*)(hq + (size_t)p * PLANE + rowo);
  bf16x8v a3 = *(const bf16x8v*)(hq + (size_t)(p + 2) * PLANE + rowo);
  f32x4v acc0 = {0.f, 0.f, 0.f, 0.f}, acc1 = acc0, acc2 = acc0;
#define LIN2_CT(CT, ACC)                                                      \
  {                                                                           \
    const unsigned short* w = Wcat + ((CT)*16 + col) * 128 + k0;              \
    bf16x8v b0 = *(const bf16x8v*)(w);                                        \
    bf16x8v b1v = *(const bf16x8v*)(w + 32);                                  \
    bf16x8v b2v = *(const bf16x8v*)(w + 64);                                  \
    bf16x8v b3v = *(const bf16x8v*)(w + 96);                                  \
    ACC = __builtin_amdgcn_mfma_f32_16x16x32_bf16(a0, b0, ACC, 0, 0, 0);      \
    ACC = __builtin_amdgcn_mfma_f32_16x16x32_bf16(a1, b1v, ACC, 0, 0, 0);     \
    ACC = __builtin_amdgcn_mfma_f32_16x16x32_bf16(a2, b2v, ACC, 0, 0, 0);     \
    ACC = __builtin_amdgcn_mfma_f32_16x16x32_bf16(a3, b3v, ACC, 0, 0, 0);     \
  }
  LIN2_CT(0, acc0) LIN2_CT(1, acc1) LIN2_CT(2, acc2)
#undef LIN2_CT
  int rbase = (lane >> 4) * 4;
  float bias0 = b2p[col], bias1 = b2p[16 + col], bias2 = b2p[32 + col];
  bool v2ok = (col < 8);   // cols 32..39 valid only
#pragma unroll
  for (int r = 0; r < 4; ++r) {
    float v0 = acc0[r] + bias0;
    float v1 = acc1[r] + bias1;
    float v2 = v2ok ? (acc2[r] + bias2) : -INFINITY;
    float mx = fmaxf(fmaxf(v0, v1), v2);
    mx = fmaxf(mx, __shfl_xor(mx, 1, 64));
    mx = fmaxf(mx, __shfl_xor(mx, 2, 64));
    mx = fmaxf(mx, __shfl_xor(mx, 4, 64));
    mx = fmaxf(mx, __shfl_xor(mx, 8, 64));
    float sm = expf(v0 - mx) + expf(v1 - mx) + (v2ok ? expf(v2 - mx) : 0.f);
    sm += __shfl_xor(sm, 1, 64);
    sm += __shfl_xor(sm, 2, 64);
    sm += __shfl_xor(sm, 4, 64);
    sm += __shfl_xor(sm, 8, 64);
    float ls = mx + logf(sm);
    size_t rowoff = (size_t)(base + rbase + r) * DOUT;
    out[rowoff + col] = v0 - ls;
    out[rowoff + 16 + col] = v1 - ls;
    if (v2ok) out[rowoff + 32 + col] = v2 - ls;
  }
}

extern "C" void kernel_launch(void* const* d_in, const int* in_sizes, int n_in,
                              void* d_out, int out_size, void* d_ws, size_t ws_size,
                              hipStream_t stream) {
  const float* x   = (const float*)d_in[0];
  const int*   ei  = (const int*)d_in[1];
  const float* W1l = (const float*)d_in[2];
  const float* b1  = (const float*)d_in[3];
  const float* W1r = (const float*)d_in[4];
  const float* W2l = (const float*)d_in[5];
  const float* b2  = (const float*)d_in[6];
  const float* W2r = (const float*)d_in[7];
  float* out = (float*)d_out;

  const int* src = ei;
  const int* dst = ei + N_EDGES;

  // Workspace (~45.3 MB): xbf | hbf | csr | row_start | bcnt/bstart/bcursor |
  // scratch(12.8M: binned then ms1) | Wcat1 | Wcat2 | b2p.  ms2 aliases xbf.
  char* ws = (char*)d_ws;
  size_t featB = (size_t)N_NODES * D * sizeof(unsigned short);  // 12.8 MB
  unsigned short* xbf = (unsigned short*)ws;
  unsigned short* hbf = (unsigned short*)(ws + featB);
  int* csr       = (int*)(ws + 2 * featB);                      // 6.4 MB
  int* row_start = csr + N_EDGES;                               // (N+1) ints
  int* bcnt      = row_start + N_NODES + 1;
  int* bstart    = bcnt + NBUCK;
  int* bcursor   = bstart + NBUCK + 1;
  char* scratch  = (char*)(bcursor + NBUCK);
  scratch = (char*)(((uintptr_t)scratch + 15) & ~(uintptr_t)15);
  unsigned* binned     = (unsigned*)scratch;                    // 6.4 MB
  unsigned short* ms1  = (unsigned short*)scratch;              // 12.8 MB (after bfine)
  unsigned short* ms2  = xbf;                                   // after lin1
  unsigned short* Wcat1 = (unsigned short*)(scratch + featB);
  unsigned short* Wcat2 = Wcat1 + 64 * 128;
  float* b2p            = (float*)(Wcat2 + 48 * 128);

  const int NCHUNK = (N_EDGES + 4095) / 4096;   // 391 chunks
  const int AGG_BLOCKS = N_NODES;               // 4 quarters x N/4 node-waves
  const int LIN_BLOCKS = ((N_NODES / 16) + 3) / 4;

  // ---- bf16 caches ----
  cvt_kernel<<<(N_NODES * D / 8 + 255) / 256, 256, 0, stream>>>(x, xbf, N_NODES * D / 8);
  wcvt_kernel<<<57, 256, 0, stream>>>(W1l, W1r, W2l, W2r, b2, Wcat1, Wcat2, b2p);

  // ---- build CSR (two-level bucket sort) ----
  hipMemsetAsync(bcnt, 0, NBUCK * sizeof(int), stream);
  bhist_kernel<<<NCHUNK, 256, 0, stream>>>(dst, bcnt, N_EDGES);
  bscan_kernel<<<1, 256, 0, stream>>>(bcnt, bstart, bcursor, N_EDGES);
  bscatter_kernel<<<NCHUNK, 256, 0, stream>>>(src, dst, bcursor, binned, N_EDGES);
  bfine_kernel<<<NBUCK, 256, 0, stream>>>(binned, bstart, row_start, csr, N_NODES, N_EDGES);

  // ---- layer 1 ----
  agg_kernel<<<AGG_BLOCKS, 256, 0, stream>>>(xbf, row_start, csr, ms1, N_NODES);
  lin1_kernel<<<LIN_BLOCKS, 256, 0, stream>>>(xbf, ms1, Wcat1, b1, hbf, N_NODES);

  // ---- layer 2 ----
  agg_kernel<<<AGG_BLOCKS, 256, 0, stream>>>(hbf, row_start, csr, ms2, N_NODES);
  lin2_kernel<<<LIN_BLOCKS, 256, 0, stream>>>(hbf, ms2, Wcat2, b2p, out, N_NODES);
}

// Round 11
// 163.368 us; speedup vs baseline: 2.4484x; 1.8538x over previous
//
#include <hip/hip_runtime.h>
#include <math.h>

#define N_NODES 100000
#define N_EDGES 1600000
#define D 64
#define DOUT 40
#define NBUCK ((N_NODES + 255) / 256)    // 391 buckets of 256 dst-nodes
#define NCHUNK ((N_EDGES + 4095) / 4096) // 391 edge chunks
#define BCAP 4864                        // bucket region capacity (mean 4096 + 12 sigma)

typedef __attribute__((ext_vector_type(8))) short bf16x8v;   // 8 bf16 (4 VGPRs)
typedef __attribute__((ext_vector_type(4))) float f32x4v;    // MFMA accumulator

__device__ inline float bf2f(unsigned u) {
  union { unsigned i; float f; } v;
  v.i = u << 16;
  return v.f;
}
__device__ inline unsigned f2bf(float f) {
  union { float f; unsigned i; } v;
  v.f = f;
  unsigned r = v.i + 0x7fffu + ((v.i >> 16) & 1u);   // RNE
  return r >> 16;
}
// packed accumulate: two bf16 from one u32 -> float2 += (v_pk_add_f32 friendly)
__device__ inline void addpk(float2& a, unsigned u) {
  union { unsigned i; float f; } lo, hi;
  lo.i = u << 16;
  hi.i = u & 0xffff0000u;
  a.x += lo.f;
  a.y += hi.f;
}

// ---------------------------------------------------------------------------
// prep_kernel: cvt(x->bf16) + weight prep + single-pass bucket scatter.
// Fixed bucket regions (BCAP) with atomic reservation => no hist/scan passes.
// ---------------------------------------------------------------------------
__global__ __launch_bounds__(256) void prep_kernel(
    const float* __restrict__ x, unsigned short* __restrict__ xbf,
    const float* __restrict__ W1l, const float* __restrict__ W1r,
    const float* __restrict__ W2l, const float* __restrict__ W2r,
    const float* __restrict__ b2, unsigned short* __restrict__ Wcat1,
    unsigned short* __restrict__ Wcat2, float* __restrict__ b2p,
    const int* __restrict__ src, const int* __restrict__ dst,
    int* __restrict__ bcnt, unsigned* __restrict__ binned) {
  __shared__ unsigned ent[4096];
  __shared__ unsigned short sbk[4096];
  __shared__ int cnt[512], scn[512], pos[512], base[512];
  int t = threadIdx.x;
  int blk = blockIdx.x;
  int gtid = blk * 256 + t;
  int nth = NCHUNK * 256;

  // ---- P0: x -> bf16 row-major (8 floats/item) ----
  const int n8 = N_NODES * D / 8;
  for (int i = gtid; i < n8; i += nth) {
    const float4* p = reinterpret_cast<const float4*>(x) + (size_t)i * 2;
    float4 a = p[0], b = p[1];
    uint4 o;
    o.x = f2bf(a.x) | (f2bf(a.y) << 16);
    o.y = f2bf(a.z) | (f2bf(a.w) << 16);
    o.z = f2bf(b.x) | (f2bf(b.y) << 16);
    o.w = f2bf(b.z) | (f2bf(b.w) << 16);
    reinterpret_cast<uint4*>(xbf)[i] = o;
  }
  // ---- P1: weight prep (tiny, grid-strided) ----
  const int NW = 64 * 128 + 48 * 128 + 48;
  for (int i = gtid; i < NW; i += nth) {
    if (i < 64 * 128) {
      int o = i >> 7, k = i & 127;
      float v = (k < 64) ? W1l[o * 64 + k] : W1r[o * 64 + (k - 64)];
      Wcat1[i] = (unsigned short)f2bf(v);
    } else if (i < 64 * 128 + 48 * 128) {
      int j = i - 64 * 128;
      int o = j >> 7, k = j & 127;
      float v = (o < DOUT) ? ((k < 64) ? W2l[o * 64 + k] : W2r[o * 64 + (k - 64)]) : 0.0f;
      Wcat2[j] = (unsigned short)f2bf(v);
    } else {
      int j = i - 64 * 128 - 48 * 128;
      b2p[j] = (j < DOUT) ? b2[j] : 0.0f;
    }
  }
  // ---- P2: chunked LDS counting-sort by bucket -> fixed-region binned ----
  cnt[t] = 0; cnt[t + 256] = 0;
  __syncthreads();
  int cbase = blk * 4096;
  int cc = min(4096, N_EDGES - cbase);
  unsigned my_e[16];
  int my_b[16];
  int nmine = 0;
#pragma unroll
  for (int i = 0; i < 16; ++i) {
    int li = t + i * 256;
    if (li < cc) {
      int s = src[cbase + li];
      int d = dst[cbase + li];
      int b = d >> 8;
      my_e[nmine] = ((unsigned)(d & 255) << 24) | (unsigned)s;
      my_b[nmine] = b;
      nmine++;
      atomicAdd(&cnt[b], 1);
    }
  }
  __syncthreads();
  scn[t] = cnt[t]; scn[t + 256] = cnt[t + 256];
  __syncthreads();
  for (int off = 1; off < 512; off <<= 1) {
    int v0 = (t >= off) ? scn[t - off] : 0;
    int v1 = scn[t + 256 - off];
    __syncthreads();
    scn[t] += v0; scn[t + 256] += v1;
    __syncthreads();
  }
  pos[t] = scn[t] - cnt[t];
  pos[t + 256] = scn[t + 256] - cnt[t + 256];
  __syncthreads();
  for (int i = 0; i < nmine; ++i) {
    int slot = atomicAdd(&pos[my_b[i]], 1);
    ent[slot] = my_e[i];
    sbk[slot] = (unsigned short)my_b[i];
  }
  __syncthreads();
  // reserve global space per touched bucket (single-pass: no pre-scan needed)
  for (int b = t; b < NBUCK; b += 256)
    if (cnt[b] > 0) base[b] = atomicAdd(&bcnt[b], cnt[b]);
  __syncthreads();
  for (int i = t; i < cc; i += 256) {
    int b = sbk[i];
    int excl = scn[b] - cnt[b];
    binned[(size_t)b * BCAP + base[b] + (i - excl)] = ent[i];
  }
}

// ---------------------------------------------------------------------------
// fine_kernel: per-bucket counting-sort (bucket cached in LDS, single global
// read of binned) -> csr (fixed regions) + per-node rs/re.
// ---------------------------------------------------------------------------
__global__ __launch_bounds__(256) void fine_kernel(
    const unsigned* __restrict__ binned, const int* __restrict__ bcnt,
    int* __restrict__ rs, int* __restrict__ re_, int* __restrict__ csr, int N) {
  __shared__ unsigned ent[BCAP];
  __shared__ int c[256], p[256], pos[256];
  int b = blockIdx.x;
  int t = threadIdx.x;
  int cc = bcnt[b];
  int s0 = b * BCAP;
  c[t] = 0;
  __syncthreads();
  for (int i = t; i < cc; i += 256) {
    unsigned u = binned[s0 + i];
    ent[i] = u;
    atomicAdd(&c[u >> 24], 1);
  }
  __syncthreads();
  p[t] = c[t];
  __syncthreads();
  for (int off = 1; off < 256; off <<= 1) {
    int v = (t >= off) ? p[t - off] : 0;
    __syncthreads();
    p[t] += v;
    __syncthreads();
  }
  int excl = p[t] - c[t];
  int node = b * 256 + t;
  if (node < N) {
    rs[node] = s0 + excl;
    re_[node] = s0 + excl + c[t];
  }
  pos[t] = excl;
  __syncthreads();
  for (int i = t; i < cc; i += 256) {
    unsigned u = ent[i];
    int slot = atomicAdd(&pos[u >> 24], 1);
    csr[s0 + slot] = (int)(u & 0xFFFFFFu);
  }
}

// ---------------------------------------------------------------------------
// Aggregation (R8 structure): one wave per node, zero LDS. 8 groups x 8
// lanes; lane loads uint4 = 8 bf16 feats (16B); x2 unroll. float2 packed
// accumulate (v_pk_add_f32). Fold shfl_xor(8,16,32); lane (g,t) writes
// feature t*8+g of the bf16 mean row.
// ---------------------------------------------------------------------------
__global__ __launch_bounds__(256) void agg_kernel(
    const unsigned short* __restrict__ feat, const int* __restrict__ rs,
    const int* __restrict__ re_, const int* __restrict__ csr,
    unsigned short* __restrict__ msbf, int N) {
  int wid = (blockIdx.x * 256 + threadIdx.x) >> 6;
  if (wid >= N) return;
  int lane = threadIdx.x & 63;
  int g = lane >> 3;
  int t = lane & 7;
  int s = rs[wid], en = re_[wid];
  float2 acc[4] = {{0.f, 0.f}, {0.f, 0.f}, {0.f, 0.f}, {0.f, 0.f}};
  int e = s + g;
  for (; e + 8 < en; e += 16) {
    int s0 = csr[e];
    int s1 = csr[e + 8];
    uint4 r0 = *reinterpret_cast<const uint4*>(feat + (size_t)s0 * D + t * 8);
    uint4 r1 = *reinterpret_cast<const uint4*>(feat + (size_t)s1 * D + t * 8);
    addpk(acc[0], r0.x); addpk(acc[1], r0.y); addpk(acc[2], r0.z); addpk(acc[3], r0.w);
    addpk(acc[0], r1.x); addpk(acc[1], r1.y); addpk(acc[2], r1.z); addpk(acc[3], r1.w);
  }
  if (e < en) {
    int s0 = csr[e];
    uint4 r0 = *reinterpret_cast<const uint4*>(feat + (size_t)s0 * D + t * 8);
    addpk(acc[0], r0.x); addpk(acc[1], r0.y); addpk(acc[2], r0.z); addpk(acc[3], r0.w);
  }
#pragma unroll
  for (int j = 0; j < 4; ++j) {
    acc[j].x += __shfl_xor(acc[j].x, 8, 64);
    acc[j].y += __shfl_xor(acc[j].y, 8, 64);
    acc[j].x += __shfl_xor(acc[j].x, 16, 64);
    acc[j].y += __shfl_xor(acc[j].y, 16, 64);
    acc[j].x += __shfl_xor(acc[j].x, 32, 64);
    acc[j].y += __shfl_xor(acc[j].y, 32, 64);
  }
  float inv = 1.0f / fmaxf((float)(en - s), 1.0f);
  float v[8] = {acc[0].x, acc[0].y, acc[1].x, acc[1].y,
                acc[2].x, acc[2].y, acc[3].x, acc[3].y};
  float mv = v[0];
#pragma unroll
  for (int j = 1; j < 8; ++j)
    if (g == j) mv = v[j];        // static-index cndmask chain (no scratch)
  msbf[(size_t)wid * D + t * 8 + g] = (unsigned short)f2bf(mv * inv);
}

// ---------------------------------------------------------------------------
// MFMA linear 1: h = relu([ms|x] @ Wcat1^T + b1), one wave per 16-node tile.
// C/D: col=lane&15, row=(lane>>4)*4+reg  [m89-verified].
// ---------------------------------------------------------------------------
__global__ __launch_bounds__(256) void lin1_kernel(
    const unsigned short* __restrict__ xbf, const unsigned short* __restrict__ msbf,
    const unsigned short* __restrict__ Wcat, const float* __restrict__ b1,
    unsigned short* __restrict__ hbf, int N) {
  int wid = (blockIdx.x * 256 + threadIdx.x) >> 6;   // tile id
  int ntiles = N >> 4;                               // 6250
  if (wid >= ntiles) return;
  int lane = threadIdx.x & 63;
  int col = lane & 15;
  int k0 = (lane >> 4) * 8;
  int base = wid * 16;
  const unsigned short* am = msbf + (size_t)(base + col) * D;
  const unsigned short* ax = xbf + (size_t)(base + col) * D;
  bf16x8v a0 = *(const bf16x8v*)(am + k0);
  bf16x8v a1 = *(const bf16x8v*)(am + 32 + k0);
  bf16x8v a2 = *(const bf16x8v*)(ax + k0);
  bf16x8v a3 = *(const bf16x8v*)(ax + 32 + k0);
  f32x4v acc0 = {0.f, 0.f, 0.f, 0.f}, acc1 = acc0, acc2 = acc0, acc3 = acc0;
#define LIN1_CT(CT, ACC)                                                      \
  {                                                                           \
    const unsigned short* w = Wcat + ((CT)*16 + col) * 128 + k0;              \
    bf16x8v b0 = *(const bf16x8v*)(w);                                        \
    bf16x8v b1v = *(const bf16x8v*)(w + 32);                                  \
    bf16x8v b2v = *(const bf16x8v*)(w + 64);                                  \
    bf16x8v b3v = *(const bf16x8v*)(w + 96);                                  \
    ACC = __builtin_amdgcn_mfma_f32_16x16x32_bf16(a0, b0, ACC, 0, 0, 0);      \
    ACC = __builtin_amdgcn_mfma_f32_16x16x32_bf16(a1, b1v, ACC, 0, 0, 0);     \
    ACC = __builtin_amdgcn_mfma_f32_16x16x32_bf16(a2, b2v, ACC, 0, 0, 0);     \
    ACC = __builtin_amdgcn_mfma_f32_16x16x32_bf16(a3, b3v, ACC, 0, 0, 0);     \
  }
  LIN1_CT(0, acc0) LIN1_CT(1, acc1) LIN1_CT(2, acc2) LIN1_CT(3, acc3)
#undef LIN1_CT
  int rbase = (lane >> 4) * 4;
  float bias0 = b1[col], bias1 = b1[16 + col], bias2 = b1[32 + col], bias3 = b1[48 + col];
#pragma unroll
  for (int r = 0; r < 4; ++r) {
    size_t rowoff = (size_t)(base + rbase + r) * D;
    hbf[rowoff + col]      = (unsigned short)f2bf(fmaxf(acc0[r] + bias0, 0.f));
    hbf[rowoff + 16 + col] = (unsigned short)f2bf(fmaxf(acc1[r] + bias1, 0.f));
    hbf[rowoff + 32 + col] = (unsigned short)f2bf(fmaxf(acc2[r] + bias2, 0.f));
    hbf[rowoff + 48 + col] = (unsigned short)f2bf(fmaxf(acc3[r] + bias3, 0.f));
  }
}

// ---------------------------------------------------------------------------
// MFMA linear 2 + log_softmax (48 cols, 40 valid; 16-lane shfl reduction)
// ---------------------------------------------------------------------------
__global__ __launch_bounds__(256) void lin2_kernel(
    const unsigned short* __restrict__ hbf, const unsigned short* __restrict__ msbf,
    const unsigned short* __restrict__ Wcat, const float* __restrict__ b2p,
    float* __restrict__ out, int N) {
  int wid = (blockIdx.x * 256 + threadIdx.x) >> 6;
  int ntiles = N >> 4;
  if (wid >= ntiles) return;
  int lane = threadIdx.x & 63;
  int col = lane & 15;
  int k0 = (lane >> 4) * 8;
  int base = wid * 16;
  const unsigned short* am = msbf + (size_t)(base + col) * D;
  const unsigned short* ah = hbf + (size_t)(base + col) * D;
  bf16x8v a0 = *(const bf16x8v*)(am + k0);
  bf16x8v a1 = *(const bf16x8v*)(am + 32 + k0);
  bf16x8v a2 = *(const bf16x8v*)(ah + k0);
  bf16x8v a3 = *(const bf16x8v*)(ah + 32 + k0);
  f32x4v acc0 = {0.f, 0.f, 0.f, 0.f}, acc1 = acc0, acc2 = acc0;
#define LIN2_CT(CT, ACC)                                                      \
  {                                                                           \
    const unsigned short* w = Wcat + ((CT)*16 + col) * 128 + k0;              \
    bf16x8v b0 = *(const bf16x8v*)(w);                                        \
    bf16x8v b1v = *(const bf16x8v*)(w + 32);                                  \
    bf16x8v b2v = *(const bf16x8v*)(w + 64);                                  \
    bf16x8v b3v = *(const bf16x8v*)(w + 96);                                  \
    ACC = __builtin_amdgcn_mfma_f32_16x16x32_bf16(a0, b0, ACC, 0, 0, 0);      \
    ACC = __builtin_amdgcn_mfma_f32_16x16x32_bf16(a1, b1v, ACC, 0, 0, 0);     \
    ACC = __builtin_amdgcn_mfma_f32_16x16x32_bf16(a2, b2v, ACC, 0, 0, 0);     \
    ACC = __builtin_amdgcn_mfma_f32_16x16x32_bf16(a3, b3v, ACC, 0, 0, 0);     \
  }
  LIN2_CT(0, acc0) LIN2_CT(1, acc1) LIN2_CT(2, acc2)
#undef LIN2_CT
  int rbase = (lane >> 4) * 4;
  float bias0 = b2p[col], bias1 = b2p[16 + col], bias2 = b2p[32 + col];
  bool v2ok = (col < 8);   // cols 32..39 valid only
#pragma unroll
  for (int r = 0; r < 4; ++r) {
    float v0 = acc0[r] + bias0;
    float v1 = acc1[r] + bias1;
    float v2 = v2ok ? (acc2[r] + bias2) : -INFINITY;
    float mx = fmaxf(fmaxf(v0, v1), v2);
    mx = fmaxf(mx, __shfl_xor(mx, 1, 64));
    mx = fmaxf(mx, __shfl_xor(mx, 2, 64));
    mx = fmaxf(mx, __shfl_xor(mx, 4, 64));
    mx = fmaxf(mx, __shfl_xor(mx, 8, 64));
    float sm = expf(v0 - mx) + expf(v1 - mx) + (v2ok ? expf(v2 - mx) : 0.f);
    sm += __shfl_xor(sm, 1, 64);
    sm += __shfl_xor(sm, 2, 64);
    sm += __shfl_xor(sm, 4, 64);
    sm += __shfl_xor(sm, 8, 64);
    float ls = mx + logf(sm);
    size_t rowoff = (size_t)(base + rbase + r) * DOUT;
    out[rowoff + col] = v0 - ls;
    out[rowoff + 16 + col] = v1 - ls;
    if (v2ok) out[rowoff + 32 + col] = v2 - ls;
  }
}

extern "C" void kernel_launch(void* const* d_in, const int* in_sizes, int n_in,
                              void* d_out, int out_size, void* d_ws, size_t ws_size,
                              hipStream_t stream) {
  const float* x   = (const float*)d_in[0];
  const int*   ei  = (const int*)d_in[1];
  const float* W1l = (const float*)d_in[2];
  const float* b1  = (const float*)d_in[3];
  const float* W1r = (const float*)d_in[4];
  const float* W2l = (const float*)d_in[5];
  const float* b2  = (const float*)d_in[6];
  const float* W2r = (const float*)d_in[7];
  float* out = (float*)d_out;

  const int* src = ei;
  const int* dst = ei + N_EDGES;

  // Workspace (~46.5 MB): xbf | hbf | csr(fixed regions) | rs | re | bcnt |
  // scratch(12.8M: binned then ms1) | Wcat1 | Wcat2 | b2p.  ms2 aliases xbf.
  char* ws = (char*)d_ws;
  size_t featB = (size_t)N_NODES * D * sizeof(unsigned short);  // 12.8 MB
  unsigned short* xbf = (unsigned short*)ws;
  unsigned short* hbf = (unsigned short*)(ws + featB);
  int* csr  = (int*)(ws + 2 * featB);                           // NBUCK*BCAP ints (~7.3 MB)
  int* rs   = csr + (size_t)NBUCK * BCAP;
  int* re_  = rs + N_NODES;
  int* bcnt = re_ + N_NODES;
  char* scratch = (char*)(bcnt + NBUCK);
  scratch = (char*)(((uintptr_t)scratch + 15) & ~(uintptr_t)15);
  unsigned* binned     = (unsigned*)scratch;                    // NBUCK*BCAP (~7.3 MB)
  unsigned short* ms1  = (unsigned short*)scratch;              // 12.8 MB (after fine)
  unsigned short* ms2  = xbf;                                   // after lin1
  unsigned short* Wcat1 = (unsigned short*)(scratch + featB);
  unsigned short* Wcat2 = Wcat1 + 64 * 128;
  float* b2p            = (float*)(Wcat2 + 48 * 128);

  const int AGG_BLOCKS = (N_NODES + 3) / 4;       // one wave per node
  const int LIN_BLOCKS = ((N_NODES / 16) + 3) / 4;

  // ---- fused prep: cvt + wcvt + single-pass bucket scatter ----
  hipMemsetAsync(bcnt, 0, NBUCK * sizeof(int), stream);
  prep_kernel<<<NCHUNK, 256, 0, stream>>>(x, xbf, W1l, W1r, W2l, W2r, b2,
                                          Wcat1, Wcat2, b2p, src, dst, bcnt, binned);
  fine_kernel<<<NBUCK, 256, 0, stream>>>(binned, bcnt, rs, re_, csr, N_NODES);

  // ---- layer 1 ----
  agg_kernel<<<AGG_BLOCKS, 256, 0, stream>>>(xbf, rs, re_, csr, ms1, N_NODES);
  lin1_kernel<<<LIN_BLOCKS, 256, 0, stream>>>(xbf, ms1, Wcat1, b1, hbf, N_NODES);

  // ---- layer 2 ----
  agg_kernel<<<AGG_BLOCKS, 256, 0, stream>>>(hbf, rs, re_, csr, ms2, N_NODES);
  lin2_kernel<<<LIN_BLOCKS, 256, 0, stream>>>(hbf, ms2, Wcat2, b2p, out, N_NODES);
}